// Round 6
// baseline (5623.550 us; speedup 1.0000x reference)
//
#include <hip/hip_runtime.h>

// RNN_85117661872189 on gfx950 — round 6: f32 inputs (verified via npz-size
// forensics), proven launch skeleton from round 5, f16-packed resident Whh.
// d_in[0] input_seq [2048][128] i32; f32: emb[128][128], Wxh_w[512][128],
// Wxh_b[512], Whh_w[512][512], Whh_b[512], dec_w[128][512], dec_b[128].
// Output f32 [2048][128][128].
//
// k_rec: one WG (512 thr) per batch row; thread = one Whh row. Row = 256
// f16-pair dwords: 184 VGPR + 56 in 117KB dynamic LDS + 16 streamed (L2).
// v_dot2_f32_f16 inner product, f32 accumulate. One barrier per step.

#define TT 2048
#define BB 128
#define HH 512
#define OO 128
#define MAGIC 123456.0f
#define NVG 184   // pair-dwords/row in VGPR (cols 0..367)
#define NLD 56    // pair-dwords/row in LDS  (cols 368..479)
#define NST 16    // pair-dwords/row streamed (cols 480..511)

typedef _Float16 h2_t __attribute__((ext_vector_type(2)));
union UF { unsigned int u; float f; h2_t h; unsigned short us[2]; };

__device__ __forceinline__ unsigned int packf16(float a, float b) {
  UF r; r.h[0] = (_Float16)a; r.h[1] = (_Float16)b; return r.u;
}
__device__ __forceinline__ float dot2a(unsigned int a, unsigned int b, float c) {
  UF x, y; x.u = a; y.u = b;
#if __has_builtin(__builtin_amdgcn_fdot2)
  return __builtin_amdgcn_fdot2(x.h, y.h, c, false);   // v_dot2_f32_f16
#else
  return fmaf((float)x.h[1], (float)y.h[1], fmaf((float)x.h[0], (float)y.h[0], c));
#endif
}
__device__ __forceinline__ unsigned short f16bits(float x) {
  UF r; r.h[0] = (_Float16)x; r.h[1] = (_Float16)0.f; return r.us[0];
}
__device__ __forceinline__ float tanh_fast(float x) {  // x pre-clamped
  float e = __expf(2.0f * x);
  return 1.0f - 2.0f / (e + 1.0f);
}
__device__ __forceinline__ float sanz(float x) {  // non-finite -> 0 (keeps probes readable)
  return (x >= -1e20f && x <= 1e20f) ? x : 0.f;
}

// ---- k_init: zero probe markers ----
extern "C" __global__ void k_init(float* __restrict__ mk) {
  if (threadIdx.x < 8) mk[threadIdx.x] = 0.f;
}

// ---- k_pre: P[id][j] = emb[id]·Wxh_w[j] + Wxh_b[j] + Whh_b[j] (all f32) ----
extern "C" __global__ __launch_bounds__(512)
void k_pre(const float* __restrict__ emb, const float* __restrict__ wxh,
           const float* __restrict__ bxh, const float* __restrict__ bhh,
           float* __restrict__ P, float* __restrict__ mk) {
  const int id = blockIdx.x;   // 0..127
  const int j = threadIdx.x;   // 0..511
  const float4* er = (const float4*)(emb + id * 128);
  const float4* wr = (const float4*)(wxh + j * 128);
  float acc = 0.f;
  #pragma unroll
  for (int c = 0; c < 32; ++c) {
    const float4 e = er[c], w = wr[c];
    acc = fmaf(e.x, w.x, fmaf(e.y, w.y, fmaf(e.z, w.z, fmaf(e.w, w.w, acc))));
  }
  P[id * HH + j] = acc + bxh[j] + bhh[j];
  if (id == 0 && j == 0) mk[0] = MAGIC;
}

// ---- k_pack: Whh f32 [512][512] -> f16 pair-dwords wpack[row][256] ----
extern "C" __global__ __launch_bounds__(256)
void k_pack(const float* __restrict__ whh, unsigned int* __restrict__ wpack) {
  const int row = blockIdx.x;      // 0..511
  const int pd = threadIdx.x;      // 0..255
  const float2 w = *(const float2*)(whh + row * 512 + 2 * pd);
  wpack[row * 256 + pd] = packf16(w.x, w.y);
}

// ---- k_pack2: streamed tail, layout [q][row] of uint4 (lane-coalesced) ----
extern "C" __global__ __launch_bounds__(512)
void k_pack2(const float* __restrict__ whh, uint4* __restrict__ wst4) {
  const int q = blockIdx.x;        // 0..3 -> pair-dwords 240+4q..243+4q
  const int t = threadIdx.x;       // row
  const float* src = whh + t * 512 + 480 + 8 * q;
  uint4 v;
  v.x = packf16(src[0], src[1]);
  v.y = packf16(src[2], src[3]);
  v.z = packf16(src[4], src[5]);
  v.w = packf16(src[6], src[7]);
  wst4[q * 512 + t] = v;
}

// ---- k_rec: nT steps; one WG per batch row; thread = one h-unit ----
extern "C" __global__ __launch_bounds__(512, 2)
void k_rec(const int* __restrict__ idx, const float* __restrict__ P,
           const unsigned int* __restrict__ wpack, const uint4* __restrict__ wst4,
           float* __restrict__ hstate, float* __restrict__ ring,
           float* __restrict__ mk, int t0, int nT) {
  extern __shared__ __align__(16) unsigned int smem[];
  unsigned int* wl = smem;                    // [NLD][512] = 114,688 B
  unsigned int* hb32 = smem + NLD * 512;      // [2][256] pair-dwords = 2 KB
  unsigned short* hb16 = (unsigned short*)hb32;
  const int tid = threadIdx.x;
  const int b = blockIdx.x;
  if (t0 == 0 && b == 0 && tid == 0) mk[1] = MAGIC;

  unsigned int wreg[NVG];
  {
    const uint4* wp = (const uint4*)(wpack + tid * 256);
    #pragma unroll
    for (int q = 0; q < NVG / 4; ++q) {       // 46 uint4 = 184 pair-dwords
      const uint4 v = wp[q];
      wreg[4 * q + 0] = v.x; wreg[4 * q + 1] = v.y;
      wreg[4 * q + 2] = v.z; wreg[4 * q + 3] = v.w;
    }
    const unsigned int* ws = wpack + tid * 256 + NVG;
    #pragma unroll
    for (int s = 0; s < NLD; ++s) wl[s * 512 + tid] = ws[s];   // setup-only
  }
  const float h0 = (t0 == 0) ? 0.f : hstate[b * HH + tid];
  hb16[tid] = f16bits(h0);                    // buffer 0 = h at t0
  float hlast = h0;
  __syncthreads();

  for (int tl = 0; tl < nT; ++tl) {
    const int rb = tl & 1, wb = rb ^ 1;
    // issue stream + pj early (hide under dot2 chain)
    uint4 w4s[4];
    #pragma unroll
    for (int q = 0; q < 4; ++q) w4s[q] = wst4[q * 512 + tid];
    const int id = idx[(t0 + tl) * BB + b];
    const float pj = P[id * HH + tid];
    const unsigned int* h = hb32 + rb * 256;
    float acc = 0.f;
    #pragma unroll
    for (int c4 = 0; c4 < NVG / 4; ++c4) {    // VGPR weights: broadcast h b128
      const uint4 h4 = *(const uint4*)(h + 4 * c4);
      acc = dot2a(wreg[4 * c4 + 0], h4.x, acc);
      acc = dot2a(wreg[4 * c4 + 1], h4.y, acc);
      acc = dot2a(wreg[4 * c4 + 2], h4.z, acc);
      acc = dot2a(wreg[4 * c4 + 3], h4.w, acc);
    }
    #pragma unroll
    for (int j = 0; j < NLD / 4; ++j) {       // LDS weights: [slot][tid], conflict-free
      const uint4 h4 = *(const uint4*)(h + NVG + 4 * j);
      acc = dot2a(wl[(4 * j + 0) * 512 + tid], h4.x, acc);
      acc = dot2a(wl[(4 * j + 1) * 512 + tid], h4.y, acc);
      acc = dot2a(wl[(4 * j + 2) * 512 + tid], h4.z, acc);
      acc = dot2a(wl[(4 * j + 3) * 512 + tid], h4.w, acc);
    }
    #pragma unroll
    for (int q = 0; q < 4; ++q) {             // streamed tail (cols 480..511)
      const uint4 h4 = *(const uint4*)(h + NVG + NLD + 4 * q);
      acc = dot2a(w4s[q].x, h4.x, acc);
      acc = dot2a(w4s[q].y, h4.y, acc);
      acc = dot2a(w4s[q].z, h4.z, acc);
      acc = dot2a(w4s[q].w, h4.w, acc);
    }
    float s = acc + pj;
    s = fminf(fmaxf(s, -30.f), 30.f);         // IEEE min/max drop NaN
    const float hv = tanh_fast(s);
    hb16[wb * 512 + tid] = f16bits(hv);
    ring[((size_t)tl * BB + b) * HH + tid] = hv;
    hlast = hv;
    __syncthreads();                          // hv visible for next step
  }
  hstate[b * HH + tid] = hlast;
  if (t0 == 0 && b == 0 && tid == 0) mk[2] = MAGIC;
}

// ---- k_dec: out rows = ring · dec_wT + dec_b (f32) ----
extern "C" __global__ __launch_bounds__(256)
void k_dec(const float* __restrict__ ring, const float* __restrict__ dw,
           const float* __restrict__ decb, float* __restrict__ out,
           float* __restrict__ mk, int t0) {
  __shared__ float hl[32][132];
  const int tid = threadIdx.x;
  const size_t r0 = (size_t)blockIdx.x * 32;
  const int oq = tid & 31, tbq = tid >> 5;
  float acc[4][4];
  #pragma unroll
  for (int rI = 0; rI < 4; ++rI)
    #pragma unroll
    for (int s = 0; s < 4; ++s) acc[rI][s] = 0.f;

  for (int cb = 0; cb < 4; ++cb) {
    __syncthreads();
    #pragma unroll
    for (int i = 0; i < 16; ++i) {            // 32x128 h tile, coalesced
      const int idx2 = i * 256 + tid;
      const int tb = idx2 >> 7, c = idx2 & 127;
      hl[tb][c] = ring[(r0 + tb) * HH + cb * 128 + c];
    }
    __syncthreads();
    #pragma unroll 2
    for (int cp2 = 0; cp2 < 32; ++cp2) {      // 4 cols per iter
      float4 h4[4];
      #pragma unroll
      for (int s = 0; s < 4; ++s) h4[s] = *(const float4*)&hl[tbq + s * 8][cp2 * 4];
      #pragma unroll
      for (int rI = 0; rI < 4; ++rI) {
        const int o = oq + rI * 32;
        const float4 w4 = *(const float4*)(dw + o * 512 + cb * 128 + cp2 * 4);
        #pragma unroll
        for (int s = 0; s < 4; ++s)
          acc[rI][s] = fmaf(w4.x, h4[s].x, fmaf(w4.y, h4[s].y,
                       fmaf(w4.z, h4[s].z, fmaf(w4.w, h4[s].w, acc[rI][s]))));
      }
    }
  }
  #pragma unroll
  for (int rI = 0; rI < 4; ++rI) {
    const int o = oq + rI * 32;
    const float db = decb[o];
    #pragma unroll
    for (int s = 0; s < 4; ++s)
      out[((size_t)t0 * BB + r0 + tbq + s * 8) * OO + o] = sanz(acc[rI][s] + db);
  }
  if (t0 == 0 && blockIdx.x == 0 && tid == 0) mk[3] = MAGIC;
}

// ---- k_probe: first missing stage -> readable code in out[0] ----
extern "C" __global__ void k_probe(const float* __restrict__ mk, float* __restrict__ out,
                                   int wsTooSmall) {
  if (wsTooSmall)     { out[0] = 100000.f; return; }
  if (mk[0] != MAGIC) { out[0] = 200000.f; return; }
  if (mk[1] != MAGIC) { out[0] = 300000.f; return; }
  if (mk[2] != MAGIC) { out[0] = 400000.f; return; }
  if (mk[3] != MAGIC) { out[0] = 500000.f; return; }
}

extern "C" void kernel_launch(void* const* d_in, const int* in_sizes, int n_in,
                              void* d_out, int out_size, void* d_ws, size_t ws_size,
                              hipStream_t stream) {
  (void)in_sizes; (void)n_in; (void)out_size;
  const int* idx = (const int*)d_in[0];
  const float* emb = (const float*)d_in[1];
  const float* wxh = (const float*)d_in[2];
  const float* bxh = (const float*)d_in[3];
  const float* whh = (const float*)d_in[4];
  const float* bhh = (const float*)d_in[5];
  const float* dw  = (const float*)d_in[6];
  const float* db  = (const float*)d_in[7];
  float* out = (float*)d_out;

  char* ws = (char*)d_ws;
  float* P = (float*)ws;                                   // @0       256 KB
  float* hstate = (float*)(ws + (256 << 10));              // @256 KB  256 KB
  float* mk = (float*)(ws + (512 << 10));                  // @512 KB    4 KB
  unsigned int* wpack = (unsigned int*)(ws + (516 << 10)); // @516 KB  512 KB
  uint4* wst4 = (uint4*)(ws + (1028 << 10));               // @1028 KB  32 KB
  float* ring = (float*)(ws + (1060 << 10));               // @1060 KB chunkT*256 KB

  int chunkT = 0;
  const int opts[6] = {2048, 512, 128, 32, 8, 2};
  for (int i = 0; i < 6; ++i) {
    const size_t need = (size_t)(1060 << 10) + (size_t)opts[i] * BB * HH * 4;
    if (ws_size >= need) { chunkT = opts[i]; break; }
  }
  if (chunkT == 0) {
    k_probe<<<1, 1, 0, stream>>>(nullptr, out, 1);
    return;
  }

  const int ldsRec = (NLD * 512 + 512) * 4;   // 116,736 B (< proven 128 KB)
  (void)hipFuncSetAttribute(reinterpret_cast<const void*>(k_rec),
                            hipFuncAttributeMaxDynamicSharedMemorySize, ldsRec);

  k_init<<<1, 64, 0, stream>>>(mk);
  k_pre<<<128, 512, 0, stream>>>(emb, wxh, bxh, bhh, P, mk);
  k_pack<<<512, 256, 0, stream>>>(whh, wpack);
  k_pack2<<<4, 512, 0, stream>>>(whh, wst4);
  for (int t0 = 0; t0 < TT; t0 += chunkT) {
    k_rec<<<BB, 512, ldsRec, stream>>>(idx, P, wpack, wst4, hstate, ring, mk, t0, chunkT);
    k_dec<<<chunkT * 4, 256, 0, stream>>>(ring, dw, db, out, mk, t0);
  }
  k_probe<<<1, 1, 0, stream>>>(mk, out, 0);
}

// Round 7
// 5156.175 us; speedup vs baseline: 1.0906x; 1.0906x over previous
//
#include <hip/hip_runtime.h>

// RNN_85117661872189 on gfx950 — round 7: readlane h-broadcast (LDS-pipe relief).
// d_in[0] input_seq [2048][128] i32; f32: emb[128][128], Wxh_w[512][128],
// Wxh_b[512], Whh_w[512][512], Whh_b[512], dec_w[128][512], dec_b[128].
// Output f32 [2048][128][128].
//
// k_rec: one WG (512 thr) per batch row; thread = one Whh row, f16 weights as
// pair-dwords: 172 VGPR + 60 in 125KB dynamic LDS + 24 re-streamed from L2
// each step (anti-LICM asm barrier). h: one ds_read_b128 per lane per step,
// then v_readlane -> SGPR -> v_dot2_f32_f16 broadcast (off the LDS pipe).
// ring/h in f16; k_dec is a dot2 GEMM on packed decP.

#define TT 2048
#define BB 128
#define HH 512
#define OO 128
#define MAGIC 123456.0f
#define NVP 43   // uint4 weight groups in VGPR   (pd   0..171)
#define NLD 15   // uint4 weight groups in LDS    (pd 172..231)
#define NSTR 6   // uint4 weight groups streamed  (pd 232..255)

typedef _Float16 h2_t __attribute__((ext_vector_type(2)));
union UF { unsigned int u; float f; h2_t h; unsigned short us[2]; };

__device__ __forceinline__ unsigned int packf16(float a, float b) {
  UF r; r.h[0] = (_Float16)a; r.h[1] = (_Float16)b; return r.u;
}
__device__ __forceinline__ float dot2a(unsigned int a, unsigned int b, float c) {
  UF x, y; x.u = a; y.u = b;
#if __has_builtin(__builtin_amdgcn_fdot2)
  return __builtin_amdgcn_fdot2(x.h, y.h, c, false);   // v_dot2_f32_f16
#else
  return fmaf((float)x.h[1], (float)y.h[1], fmaf((float)x.h[0], (float)y.h[0], c));
#endif
}
__device__ __forceinline__ unsigned short f16bits(float x) {
  UF r; r.h[0] = (_Float16)x; r.h[1] = (_Float16)0.f; return r.us[0];
}
__device__ __forceinline__ float tanh_fast(float x) {  // x pre-clamped
  float e = __expf(2.0f * x);
  return 1.0f - 2.0f / (e + 1.0f);
}
__device__ __forceinline__ float sanz(float x) {  // non-finite -> 0 (probe-readable)
  return (x >= -1e20f && x <= 1e20f) ? x : 0.f;
}
__device__ __forceinline__ unsigned int rdlane(unsigned int v, int l) {
#if __has_builtin(__builtin_amdgcn_readlane)
  return (unsigned int)__builtin_amdgcn_readlane((int)v, l);
#else
  return (unsigned int)__shfl((int)v, l, 64);
#endif
}

// ---- k_init: zero probe markers ----
extern "C" __global__ void k_init(float* __restrict__ mk) {
  if (threadIdx.x < 8) mk[threadIdx.x] = 0.f;
}

// ---- k_pre: P[id][j] = emb[id]·Wxh_w[j] + Wxh_b[j] + Whh_b[j] (f32) ----
extern "C" __global__ __launch_bounds__(512)
void k_pre(const float* __restrict__ emb, const float* __restrict__ wxh,
           const float* __restrict__ bxh, const float* __restrict__ bhh,
           float* __restrict__ P, float* __restrict__ mk) {
  const int id = blockIdx.x;
  const int j = threadIdx.x;
  const float4* er = (const float4*)(emb + id * 128);
  const float4* wr = (const float4*)(wxh + j * 128);
  float acc = 0.f;
  #pragma unroll
  for (int c = 0; c < 32; ++c) {
    const float4 e = er[c], w = wr[c];
    acc = fmaf(e.x, w.x, fmaf(e.y, w.y, fmaf(e.z, w.z, fmaf(e.w, w.w, acc))));
  }
  P[id * HH + j] = acc + bxh[j] + bhh[j];
  if (id == 0 && j == 0) mk[0] = MAGIC;
}

// ---- k_pack: Whh f32 [512][512] -> f16 pair-dwords wpack[row][256] ----
extern "C" __global__ __launch_bounds__(256)
void k_pack(const float* __restrict__ whh, unsigned int* __restrict__ wpack) {
  const int row = blockIdx.x;      // 0..511
  const int pd = threadIdx.x;      // 0..255
  const float2 w = *(const float2*)(whh + row * 512 + 2 * pd);
  wpack[row * 256 + pd] = packf16(w.x, w.y);
}

// ---- k_pack3: streamed tail [q][row] uint4 (lane-coalesced per step) ----
extern "C" __global__ __launch_bounds__(512)
void k_pack3(const float* __restrict__ whh, uint4* __restrict__ wstr4) {
  const int q = blockIdx.x;        // 0..5 -> cols 464+8q .. 471+8q
  const int t = threadIdx.x;       // row
  const float* src = whh + t * 512 + 464 + 8 * q;
  uint4 v;
  v.x = packf16(src[0], src[1]);
  v.y = packf16(src[2], src[3]);
  v.z = packf16(src[4], src[5]);
  v.w = packf16(src[6], src[7]);
  wstr4[q * 512 + t] = v;
}

// ---- k_packd: decP4[c4*128+o] = f16 pairs of dec_w[o][8c4..8c4+7] ----
extern "C" __global__ __launch_bounds__(256)
void k_packd(const float* __restrict__ dw, uint4* __restrict__ decP4) {
  const int id = blockIdx.x * 256 + threadIdx.x;   // 0..8191
  const int c4 = id >> 7, o = id & 127;
  const float* src = dw + o * 512 + 8 * c4;
  uint4 v;
  v.x = packf16(src[0], src[1]);
  v.y = packf16(src[2], src[3]);
  v.z = packf16(src[4], src[5]);
  v.w = packf16(src[6], src[7]);
  decP4[id] = v;
}

// ---- k_rec: nT steps; one WG per batch row; thread = one h-unit ----
#define GSTEP(W4, g)                                              \
  {                                                               \
    const unsigned int bc0 = rdlane(hv.x, (g));                   \
    const unsigned int bc1 = rdlane(hv.y, (g));                   \
    const unsigned int bc2 = rdlane(hv.z, (g));                   \
    const unsigned int bc3 = rdlane(hv.w, (g));                   \
    a0 = dot2a((W4).x, bc0, a0);                                  \
    a1 = dot2a((W4).y, bc1, a1);                                  \
    a2 = dot2a((W4).z, bc2, a2);                                  \
    a3 = dot2a((W4).w, bc3, a3);                                  \
  }

extern "C" __global__
__attribute__((amdgpu_flat_work_group_size(512, 512), amdgpu_waves_per_eu(2, 2)))
void k_rec(const int* __restrict__ idx, const float* __restrict__ P,
           const unsigned int* __restrict__ wpack, const uint4* __restrict__ wstr4,
           float* __restrict__ hstate, unsigned short* __restrict__ ring16,
           float* __restrict__ mk, int t0, int nT) {
  extern __shared__ __align__(16) unsigned char smem[];
  uint4* wl4 = (uint4*)smem;                                   // [NLD][512] 122,880 B
  unsigned short* hb16 = (unsigned short*)(smem + NLD * 512 * 16);  // [2][512]
  const uint4* hb4 = (const uint4*)hb16;                       // 64 uint4 per buffer
  const int tid = threadIdx.x;
  const int b = blockIdx.x;
  const int lane = tid & 63;
  if (t0 == 0 && b == 0 && tid == 0) mk[1] = MAGIC;

  uint4 wreg[NVP];
  {
    const uint4* wp = (const uint4*)(wpack + (size_t)tid * 256);
    #pragma unroll
    for (int q = 0; q < NVP; ++q) wreg[q] = wp[q];
    #pragma unroll
    for (int s = 0; s < NLD; ++s) wl4[s * 512 + tid] = wp[NVP + s];
  }
  const float h0 = (t0 == 0) ? 0.f : hstate[b * HH + tid];
  hb16[tid] = f16bits(h0);
  float hlast = h0;
  __syncthreads();

  for (int tl = 0; tl < nT; ++tl) {
    asm volatile("" ::: "memory");            // defeat LICM: keep stream per-step
    const int rb = tl & 1, wb = rb ^ 1;
    uint4 st[NSTR];
    #pragma unroll
    for (int q = 0; q < NSTR; ++q) st[q] = wstr4[q * 512 + tid];  // L2-hot
    const int id = idx[(t0 + tl) * BB + b];
    const float pj = P[id * HH + tid];
    const uint4 hv = hb4[rb * 64 + lane];     // lane's 4 h pair-dwords
    float a0 = 0.f, a1 = 0.f, a2 = 0.f, a3 = 0.f;
    #pragma unroll
    for (int g = 0; g < NVP; ++g) GSTEP(wreg[g], g);
    #pragma unroll
    for (int g2 = 0; g2 < NLD; ++g2) {
      const uint4 w4 = wl4[g2 * 512 + tid];   // conflict-free b128
      GSTEP(w4, NVP + g2);
    }
    #pragma unroll
    for (int q = 0; q < NSTR; ++q) GSTEP(st[q], NVP + NLD + q);
    float s = a0 + a1 + a2 + a3 + pj;
    s = fminf(fmaxf(s, -30.f), 30.f);         // IEEE min/max drop NaN
    const float hvf = tanh_fast(s);
    const unsigned short h16 = f16bits(hvf);
    hb16[wb * 512 + tid] = h16;
    ring16[((size_t)tl * BB + b) * HH + tid] = h16;
    hlast = hvf;
    __syncthreads();
  }
  hstate[b * HH + tid] = hlast;
  if (t0 == 0 && b == 0 && tid == 0) mk[2] = MAGIC;
}

// ---- k_dec: out rows = ring(f16) · decP + dec_b; 64 rows x 128 o per block ----
extern "C" __global__ __launch_bounds__(512)
void k_dec(const uint4* __restrict__ ring4, const uint4* __restrict__ decP4,
           const float* __restrict__ decb, float* __restrict__ out,
           float* __restrict__ mk, int t0) {
  extern __shared__ __align__(16) unsigned char smem[];
  uint4* hl4 = (uint4*)smem;                  // [64 rows][64 c4] = 65,536 B
  const int tid = threadIdx.x;
  const size_t r0 = (size_t)blockIdx.x * 64;
  #pragma unroll
  for (int i = 0; i < 8; ++i) {               // load 64x512 f16 h tile, coalesced
    const int u = i * 512 + tid;
    const int row = u >> 6, c4 = u & 63;
    hl4[u] = ring4[(r0 + row) * 64 + c4];
  }
  __syncthreads();
  const int oq = tid & 31, tq = tid >> 5;     // o in {oq+32r}, row in {tq+16s}
  float acc[4][4];
  #pragma unroll
  for (int r = 0; r < 4; ++r)
    #pragma unroll
    for (int s = 0; s < 4; ++s) acc[r][s] = 0.f;
  #pragma unroll 2
  for (int c4 = 0; c4 < 64; ++c4) {
    uint4 h4[4], d4[4];
    #pragma unroll
    for (int s = 0; s < 4; ++s) h4[s] = hl4[(tq + 16 * s) * 64 + c4];
    #pragma unroll
    for (int r = 0; r < 4; ++r) d4[r] = decP4[c4 * 128 + oq + 32 * r];
    #pragma unroll
    for (int r = 0; r < 4; ++r)
      #pragma unroll
      for (int s = 0; s < 4; ++s) {
        acc[r][s] = dot2a(d4[r].x, h4[s].x, acc[r][s]);
        acc[r][s] = dot2a(d4[r].y, h4[s].y, acc[r][s]);
        acc[r][s] = dot2a(d4[r].z, h4[s].z, acc[r][s]);
        acc[r][s] = dot2a(d4[r].w, h4[s].w, acc[r][s]);
      }
  }
  #pragma unroll
  for (int r = 0; r < 4; ++r) {
    const float db = decb[oq + 32 * r];
    #pragma unroll
    for (int s = 0; s < 4; ++s) {
      const size_t g = r0 + tq + 16 * s;
      out[((size_t)t0 * BB + g) * OO + oq + 32 * r] = sanz(acc[r][s] + db);
    }
  }
  if (t0 == 0 && blockIdx.x == 0 && tid == 0) mk[3] = MAGIC;
}

// ---- k_probe: first missing stage -> readable code in out[0] ----
extern "C" __global__ void k_probe(const float* __restrict__ mk, float* __restrict__ out,
                                   int wsTooSmall) {
  if (wsTooSmall)     { out[0] = 100000.f; return; }
  if (mk[0] != MAGIC) { out[0] = 200000.f; return; }
  if (mk[1] != MAGIC) { out[0] = 300000.f; return; }
  if (mk[2] != MAGIC) { out[0] = 400000.f; return; }
  if (mk[3] != MAGIC) { out[0] = 500000.f; return; }
}

extern "C" void kernel_launch(void* const* d_in, const int* in_sizes, int n_in,
                              void* d_out, int out_size, void* d_ws, size_t ws_size,
                              hipStream_t stream) {
  (void)in_sizes; (void)n_in; (void)out_size;
  const int* idx = (const int*)d_in[0];
  const float* emb = (const float*)d_in[1];
  const float* wxh = (const float*)d_in[2];
  const float* bxh = (const float*)d_in[3];
  const float* whh = (const float*)d_in[4];
  const float* bhh = (const float*)d_in[5];
  const float* dw  = (const float*)d_in[6];
  const float* db  = (const float*)d_in[7];
  float* out = (float*)d_out;

  char* ws = (char*)d_ws;
  float* P = (float*)ws;                                    // @0       256 KB
  float* hstate = (float*)(ws + (256 << 10));               // @256 KB  256 KB
  float* mk = (float*)(ws + (512 << 10));                   // @512 KB    4 KB
  unsigned int* wpack = (unsigned int*)(ws + (516 << 10));  // @516 KB  512 KB
  uint4* wstr4 = (uint4*)(ws + (1028 << 10));               // @1028 KB  48 KB
  uint4* decP4 = (uint4*)(ws + (1076 << 10));               // @1076 KB 128 KB
  unsigned short* ring16 = (unsigned short*)(ws + (1204 << 10));  // @1204 KB

  int chunkT = 0;
  const int opts[8] = {2048, 1024, 768, 512, 256, 128, 32, 8};
  for (int i = 0; i < 8; ++i) {
    const size_t need = (size_t)(1204 << 10) + (size_t)opts[i] * BB * HH * 2;
    if (ws_size >= need) { chunkT = opts[i]; break; }
  }
  if (chunkT == 0) {
    k_probe<<<1, 1, 0, stream>>>(nullptr, out, 1);
    return;
  }

  const int ldsRec = NLD * 512 * 16 + 2048;   // 124,928 B
  const int ldsDec = 64 * 64 * 16;            //  65,536 B
  (void)hipFuncSetAttribute(reinterpret_cast<const void*>(k_rec),
                            hipFuncAttributeMaxDynamicSharedMemorySize, ldsRec);
  (void)hipFuncSetAttribute(reinterpret_cast<const void*>(k_dec),
                            hipFuncAttributeMaxDynamicSharedMemorySize, ldsDec);

  k_init<<<1, 64, 0, stream>>>(mk);
  k_pre<<<128, 512, 0, stream>>>(emb, wxh, bxh, bhh, P, mk);
  k_pack<<<512, 256, 0, stream>>>(whh, wpack);
  k_pack3<<<6, 512, 0, stream>>>(whh, wstr4);
  k_packd<<<32, 256, 0, stream>>>(dw, decP4);
  for (int t0 = 0; t0 < TT; t0 += chunkT) {
    k_rec<<<BB, 512, ldsRec, stream>>>(idx, P, wpack, wstr4, hstate, ring16, mk, t0, chunkT);
    k_dec<<<chunkT * 2, 512, ldsDec, stream>>>((const uint4*)ring16, decP4, db, out, mk, t0);
  }
  k_probe<<<1, 1, 0, stream>>>(mk, out, 0);
}

// Round 8
// 4945.174 us; speedup vs baseline: 1.1372x; 1.0427x over previous
//
#include <hip/hip_runtime.h>

// RNN_85117661872189 on gfx950 — round 8: resident weights for real.
// Round-7 bug: asm memory clobber forced per-step L2 re-load of all weights.
// Fix: no clobber; 46 NAMED uint4 weight regs (can't be array-demoted) +
// 18 uint4-groups in 149.5KB dynamic LDS. readlane->dot2 broadcast (verified).
// d_in[0] input_seq [2048][128] i32; f32: emb[128][128], Wxh_w[512][128],
// Wxh_b[512], Whh_w[512][512], Whh_b[512], dec_w[128][512], dec_b[128].
// Output f32 [2048][128][128].

#define TT 2048
#define BB 128
#define HH 512
#define OO 128
#define MAGIC 123456.0f
#define NLDG 18   // uint4 weight groups in LDS (groups 46..63)

typedef _Float16 h2_t __attribute__((ext_vector_type(2)));
union UF { unsigned int u; float f; h2_t h; unsigned short us[2]; };

__device__ __forceinline__ unsigned int packf16(float a, float b) {
  UF r; r.h[0] = (_Float16)a; r.h[1] = (_Float16)b; return r.u;
}
__device__ __forceinline__ float dot2a(unsigned int a, unsigned int b, float c) {
  UF x, y; x.u = a; y.u = b;
#if __has_builtin(__builtin_amdgcn_fdot2)
  return __builtin_amdgcn_fdot2(x.h, y.h, c, false);   // v_dot2_f32_f16
#else
  return fmaf((float)x.h[1], (float)y.h[1], fmaf((float)x.h[0], (float)y.h[0], c));
#endif
}
__device__ __forceinline__ unsigned short f16bits(float x) {
  UF r; r.h[0] = (_Float16)x; r.h[1] = (_Float16)0.f; return r.us[0];
}
__device__ __forceinline__ float tanh_fast(float x) {  // x pre-clamped
  float e = __expf(2.0f * x);
  return 1.0f - 2.0f / (e + 1.0f);
}
__device__ __forceinline__ float sanz(float x) {  // non-finite -> 0 (probe-readable)
  return (x >= -1e20f && x <= 1e20f) ? x : 0.f;
}
__device__ __forceinline__ unsigned int rdlane(unsigned int v, int l) {
#if __has_builtin(__builtin_amdgcn_readlane)
  return (unsigned int)__builtin_amdgcn_readlane((int)v, l);
#else
  return (unsigned int)__shfl((int)v, l, 64);
#endif
}

// ---- k_init: zero probe markers ----
extern "C" __global__ void k_init(float* __restrict__ mk) {
  if (threadIdx.x < 8) mk[threadIdx.x] = 0.f;
}

// ---- k_pre: P[id][j] = emb[id]·Wxh_w[j] + Wxh_b[j] + Whh_b[j] (f32) ----
extern "C" __global__ __launch_bounds__(512)
void k_pre(const float* __restrict__ emb, const float* __restrict__ wxh,
           const float* __restrict__ bxh, const float* __restrict__ bhh,
           float* __restrict__ P, float* __restrict__ mk) {
  const int id = blockIdx.x;
  const int j = threadIdx.x;
  const float4* er = (const float4*)(emb + id * 128);
  const float4* wr = (const float4*)(wxh + j * 128);
  float acc = 0.f;
  #pragma unroll
  for (int c = 0; c < 32; ++c) {
    const float4 e = er[c], w = wr[c];
    acc = fmaf(e.x, w.x, fmaf(e.y, w.y, fmaf(e.z, w.z, fmaf(e.w, w.w, acc))));
  }
  P[id * HH + j] = acc + bxh[j] + bhh[j];
  if (id == 0 && j == 0) mk[0] = MAGIC;
}

// ---- k_pack: Whh f32 [512][512] -> f16 pair-dwords wpack[row][256] ----
extern "C" __global__ __launch_bounds__(256)
void k_pack(const float* __restrict__ whh, unsigned int* __restrict__ wpack) {
  const int row = blockIdx.x;      // 0..511
  const int pd = threadIdx.x;      // 0..255
  const float2 w = *(const float2*)(whh + row * 512 + 2 * pd);
  wpack[row * 256 + pd] = packf16(w.x, w.y);
}

// ---- k_packd: decP4[c4*128+o] = f16 pairs of dec_w[o][8c4..8c4+7] ----
extern "C" __global__ __launch_bounds__(256)
void k_packd(const float* __restrict__ dw, uint4* __restrict__ decP4) {
  const int id = blockIdx.x * 256 + threadIdx.x;   // 0..8191
  const int c4 = id >> 7, o = id & 127;
  const float* src = dw + o * 512 + 8 * c4;
  uint4 v;
  v.x = packf16(src[0], src[1]);
  v.y = packf16(src[2], src[3]);
  v.z = packf16(src[4], src[5]);
  v.w = packf16(src[6], src[7]);
  decP4[id] = v;
}

// group g covers pair-dwords 4g..4g+3 (= h cols 8g..8g+7); lane g of the wave
// holds exactly those 4 h pair-dwords in hv -> readlane broadcast (verified r7).
#define GSTEP(W4, g)                                    \
  {                                                     \
    a0 = dot2a((W4).x, rdlane(hv.x, (g)), a0);          \
    a1 = dot2a((W4).y, rdlane(hv.y, (g)), a1);          \
    a2 = dot2a((W4).z, rdlane(hv.z, (g)), a2);          \
    a3 = dot2a((W4).w, rdlane(hv.w, (g)), a3);          \
  }

#define WL(X) \
  X(0) X(1) X(2) X(3) X(4) X(5) X(6) X(7) X(8) X(9) \
  X(10) X(11) X(12) X(13) X(14) X(15) X(16) X(17) X(18) X(19) \
  X(20) X(21) X(22) X(23) X(24) X(25) X(26) X(27) X(28) X(29) \
  X(30) X(31) X(32) X(33) X(34) X(35) X(36) X(37) X(38) X(39) \
  X(40) X(41) X(42) X(43) X(44) X(45)
#define LOADW(i) const uint4 w_##i = wp[i];
#define USEW(i) GSTEP(w_##i, i)

// ---- k_rec: 2048 steps; one WG (512 thr) per batch row; thread = one h-row ----
extern "C" __global__ __launch_bounds__(512, 2)
void k_rec(const int* __restrict__ idx, const float* __restrict__ P,
           const unsigned int* __restrict__ wpack,
           float* __restrict__ hstate, unsigned short* __restrict__ ring16,
           float* __restrict__ mk, int t0, int nT) {
  extern __shared__ __align__(16) unsigned char smem[];
  uint4* wl4 = (uint4*)smem;                                   // [NLDG][512] 147,456 B
  unsigned short* hb16 = (unsigned short*)(smem + NLDG * 512 * 16);  // [2][512]
  const uint4* hb4 = (const uint4*)hb16;
  const int tid = threadIdx.x;
  const int b = blockIdx.x;
  const int lane = tid & 63;
  if (t0 == 0 && b == 0 && tid == 0) mk[1] = MAGIC;

  const uint4* wp = (const uint4*)(wpack + (size_t)tid * 256);
  WL(LOADW)                                   // 46 named uint4 = 184 VGPR dwords
  #pragma unroll
  for (int s = 0; s < NLDG; ++s) wl4[s * 512 + tid] = wp[46 + s];

  const float h0 = (t0 == 0) ? 0.f : hstate[b * HH + tid];
  hb16[tid] = f16bits(h0);
  float hlast = h0;
  __syncthreads();

  for (int tl = 0; tl < nT; ++tl) {
    const int rb = tl & 1, wb = rb ^ 1;
    const int id = idx[(t0 + tl) * BB + b];   // wave-uniform -> s_load
    const float pj = P[id * HH + tid];
    const uint4 hv = hb4[rb * 64 + lane];     // lane's 4 h pair-dwords
    float a0 = 0.f, a1 = 0.f, a2 = 0.f, a3 = 0.f;
    #pragma unroll
    for (int s = 0; s < NLDG; ++s) {          // LDS-resident groups (reads issue early)
      const uint4 w4 = wl4[s * 512 + tid];    // conflict-free b128
      GSTEP(w4, 46 + s);
    }
    WL(USEW)                                  // VGPR-resident groups
    float s = a0 + a1 + a2 + a3 + pj;
    s = fminf(fmaxf(s, -30.f), 30.f);         // IEEE min/max drop NaN
    const float hvf = tanh_fast(s);
    const unsigned short h16 = f16bits(hvf);
    hb16[wb * 512 + tid] = h16;
    ring16[((size_t)tl * BB + b) * HH + tid] = h16;
    hlast = hvf;
    __syncthreads();                          // h[wb] visible for next step
  }
  hstate[b * HH + tid] = hlast;
  if (t0 == 0 && b == 0 && tid == 0) mk[2] = MAGIC;
}

// ---- k_dec: out rows = ring(f16) · decP + dec_b; 64 rows x 128 o per block ----
extern "C" __global__ __launch_bounds__(512)
void k_dec(const uint4* __restrict__ ring4, const uint4* __restrict__ decP4,
           const float* __restrict__ decb, float* __restrict__ out,
           float* __restrict__ mk, int t0) {
  extern __shared__ __align__(16) unsigned char smem[];
  uint4* hl4 = (uint4*)smem;                  // [64 rows][64 c4] = 65,536 B
  const int tid = threadIdx.x;
  const size_t r0 = (size_t)blockIdx.x * 64;
  #pragma unroll
  for (int i = 0; i < 8; ++i) {               // 64x512 f16 h tile, coalesced
    const int u = i * 512 + tid;
    hl4[u] = ring4[(r0 + (u >> 6)) * 64 + (u & 63)];
  }
  __syncthreads();
  const int oq = tid & 31, tq = tid >> 5;     // o in {oq+32r}, row in {tq+16s}
  float acc[4][4];
  #pragma unroll
  for (int r = 0; r < 4; ++r)
    #pragma unroll
    for (int s = 0; s < 4; ++s) acc[r][s] = 0.f;
  #pragma unroll 2
  for (int c4 = 0; c4 < 64; ++c4) {
    uint4 h4[4], d4[4];
    #pragma unroll
    for (int s = 0; s < 4; ++s) h4[s] = hl4[(tq + 16 * s) * 64 + c4];
    #pragma unroll
    for (int r = 0; r < 4; ++r) d4[r] = decP4[c4 * 128 + oq + 32 * r];
    #pragma unroll
    for (int r = 0; r < 4; ++r)
      #pragma unroll
      for (int s = 0; s < 4; ++s) {
        acc[r][s] = dot2a(d4[r].x, h4[s].x, acc[r][s]);
        acc[r][s] = dot2a(d4[r].y, h4[s].y, acc[r][s]);
        acc[r][s] = dot2a(d4[r].z, h4[s].z, acc[r][s]);
        acc[r][s] = dot2a(d4[r].w, h4[s].w, acc[r][s]);
      }
  }
  #pragma unroll
  for (int r = 0; r < 4; ++r) {
    const float db = decb[oq + 32 * r];
    #pragma unroll
    for (int s = 0; s < 4; ++s) {
      const size_t g = r0 + tq + 16 * s;
      out[((size_t)t0 * BB + g) * OO + oq + 32 * r] = sanz(acc[r][s] + db);
    }
  }
  if (t0 == 0 && blockIdx.x == 0 && tid == 0) mk[3] = MAGIC;
}

// ---- k_probe: first missing stage -> readable code in out[0] ----
extern "C" __global__ void k_probe(const float* __restrict__ mk, float* __restrict__ out,
                                   int wsTooSmall) {
  if (wsTooSmall)     { out[0] = 100000.f; return; }
  if (mk[0] != MAGIC) { out[0] = 200000.f; return; }
  if (mk[1] != MAGIC) { out[0] = 300000.f; return; }
  if (mk[2] != MAGIC) { out[0] = 400000.f; return; }
  if (mk[3] != MAGIC) { out[0] = 500000.f; return; }
}

extern "C" void kernel_launch(void* const* d_in, const int* in_sizes, int n_in,
                              void* d_out, int out_size, void* d_ws, size_t ws_size,
                              hipStream_t stream) {
  (void)in_sizes; (void)n_in; (void)out_size;
  const int* idx = (const int*)d_in[0];
  const float* emb = (const float*)d_in[1];
  const float* wxh = (const float*)d_in[2];
  const float* bxh = (const float*)d_in[3];
  const float* whh = (const float*)d_in[4];
  const float* bhh = (const float*)d_in[5];
  const float* dw  = (const float*)d_in[6];
  const float* db  = (const float*)d_in[7];
  float* out = (float*)d_out;

  char* ws = (char*)d_ws;
  float* P = (float*)ws;                                    // @0       256 KB
  float* hstate = (float*)(ws + (256 << 10));               // @256 KB  256 KB
  float* mk = (float*)(ws + (512 << 10));                   // @512 KB    4 KB
  unsigned int* wpack = (unsigned int*)(ws + (516 << 10));  // @516 KB  512 KB
  uint4* decP4 = (uint4*)(ws + (1076 << 10));               // @1076 KB 128 KB
  unsigned short* ring16 = (unsigned short*)(ws + (1204 << 10));  // @1204 KB

  int chunkT = 0;
  const int opts[8] = {2048, 1024, 768, 512, 256, 128, 32, 8};
  for (int i = 0; i < 8; ++i) {
    const size_t need = (size_t)(1204 << 10) + (size_t)opts[i] * BB * HH * 2;
    if (ws_size >= need) { chunkT = opts[i]; break; }
  }
  if (chunkT == 0) {
    k_probe<<<1, 1, 0, stream>>>(nullptr, out, 1);
    return;
  }

  const int ldsRec = NLDG * 512 * 16 + 2048;  // 149,504 B (<= 160 KB cap)
  const int ldsDec = 64 * 64 * 16;            //  65,536 B
  (void)hipFuncSetAttribute(reinterpret_cast<const void*>(k_rec),
                            hipFuncAttributeMaxDynamicSharedMemorySize, ldsRec);
  (void)hipFuncSetAttribute(reinterpret_cast<const void*>(k_dec),
                            hipFuncAttributeMaxDynamicSharedMemorySize, ldsDec);

  k_init<<<1, 64, 0, stream>>>(mk);
  k_pre<<<128, 512, 0, stream>>>(emb, wxh, bxh, bhh, P, mk);
  k_pack<<<512, 256, 0, stream>>>(whh, wpack);
  k_packd<<<32, 256, 0, stream>>>(dw, decP4);
  for (int t0 = 0; t0 < TT; t0 += chunkT) {
    k_rec<<<BB, 512, ldsRec, stream>>>(idx, P, wpack, hstate, ring16, mk, t0, chunkT);
    k_dec<<<chunkT * 2, 512, ldsDec, stream>>>((const uint4*)ring16, decP4, db, out, mk, t0);
  }
  k_probe<<<1, 1, 0, stream>>>(mk, out, 0);
}